// Round 6
// baseline (1418.905 us; speedup 1.0000x reference)
//
#include <hip/hip_runtime.h>

#define BB 32768
#define FF 16
#define HH 64
#define OO 32
#define EE 16

#define NB   64     // batches per block
#define TOKS 20     // floats per tok row in LDS (80B: odd multiple of 16B -> conflict-free reads)
#define KVS  520    // floats per batch kv region (k 256 + v 256 + 8 pad)

typedef float v2f __attribute__((ext_vector_type(2)));

__device__ __forceinline__ v2f pkfma(v2f a, v2f b, v2f c) {
    return __builtin_elementwise_fma(a, b, c);   // -> v_pk_fma_f32 on gfx950
}

// Full-rate DPP butterfly sum over each aligned 16-lane group (replicated).
__device__ __forceinline__ float sum16(float v) {
    int i;
    i = __builtin_amdgcn_update_dpp(0, __float_as_int(v), 0xB1,  0xF, 0xF, true); v += __int_as_float(i); // xor 1
    i = __builtin_amdgcn_update_dpp(0, __float_as_int(v), 0x4E,  0xF, 0xF, true); v += __int_as_float(i); // xor 2
    i = __builtin_amdgcn_update_dpp(0, __float_as_int(v), 0x141, 0xF, 0xF, true); v += __int_as_float(i); // half-mirror
    i = __builtin_amdgcn_update_dpp(0, __float_as_int(v), 0x140, 0xF, 0xF, true); v += __int_as_float(i); // row mirror
    return v;
}

// waves_per_eu(4,4): LDS (130KB) caps us at 1 block/CU = 4 waves/EU anyway;
// pinning min=max=4 gives the allocator the full 128-VGPR budget instead of
// its default 8-waves/EU target (64 VGPR), which spilled ~150 floats/thread
// in round 5 (WRITE_SIZE 320MB of scratch).
__global__ __launch_bounds__(1024) __attribute__((amdgpu_waves_per_eu(4, 4)))
void spinn_fused_kernel(
    const float* __restrict__ x,
    const float* __restrict__ W1, const float* __restrict__ b1,
    const float* __restrict__ W2, const float* __restrict__ b2,
    const float* __restrict__ W3, const float* __restrict__ b3,
    const float* __restrict__ Wp, const float* __restrict__ bp,
    const float* __restrict__ Wqkv, const float* __restrict__ bqkv,
    const float* __restrict__ Wo,   const float* __restrict__ bo,
    const float* __restrict__ Wf,   const float* __restrict__ bf,
    float* __restrict__ out)
{
    // One buffer, two lives: [phase 1-2] tok rows (1024 x 20 floats = 80KB),
    // [phase 2+] kv per batch (64 x 520 floats = 130KB). Overwrite is safe after barrier 2.
    __shared__ __align__(16) float lds[NB * KVS];

    const int t = threadIdx.x;

    // ================= Phase 1: per-feature subnets =================
    // wave w = feature w (wave-uniform weights -> s_load), lane l = batch.
    {
        const int w = t >> 6;
        const int l = t & 63;
        const int b = blockIdx.x * NB + l;

        const float* __restrict__ w1  = W1 + w*HH;
        const float* __restrict__ bb1 = b1 + w*HH;
        const float* __restrict__ w2  = W2 + w*HH*HH;
        const float* __restrict__ bb2 = b2 + w*HH;
        const float* __restrict__ w3  = W3 + w*HH*OO;
        const float* __restrict__ bb3 = b3 + w*OO;

        const float xv = x[(size_t)b*FF + w];

        // Layers 1+2+3 with k-chunking (2 x 32): per chunk, accumulate h2-chunk
        // over all j, apply leaky, and immediately fold into to2 (layer 3).
        // Peak live set: 16 v2f chunk + 16 v2f to2 ~= 64 VGPRs (vs 110+ unchunked).
        v2f to2[OO/2];
        #pragma unroll
        for (int o = 0; o < OO/2; ++o) to2[o] = *(const v2f*)(bb3 + 2*o);

        #pragma unroll
        for (int c = 0; c < 2; ++c) {
            const int k0 = c*32;   // h-chunk base
            v2f hc[16];
            #pragma unroll
            for (int k = 0; k < 16; ++k) hc[k] = *(const v2f*)(bb2 + k0 + 2*k);

            #pragma unroll 4
            for (int j = 0; j < HH; ++j) {
                float h1 = fmaf(xv, w1[j], bb1[j]);
                h1 = (h1 >= 0.f) ? h1 : 0.01f*h1;
                v2f hd; hd[0] = h1; hd[1] = h1;
                const v2f* wr = (const v2f*)(w2 + j*HH + k0);
                #pragma unroll
                for (int k = 0; k < 16; ++k)
                    hc[k] = pkfma(hd, wr[k], hc[k]);
            }

            // leaky + layer-3 partial
            #pragma unroll
            for (int k = 0; k < 32; ++k) {
                float hv = hc[k>>1][k&1];
                hv = (hv >= 0.f) ? hv : 0.01f*hv;
                v2f hd; hd[0] = hv; hd[1] = hv;
                const v2f* wr = (const v2f*)(w3 + (k0 + k)*OO);
                #pragma unroll
                for (int o = 0; o < OO/2; ++o)
                    to2[o] = pkfma(hd, wr[o], to2[o]);
            }
        }

        // proj O->E
        v2f te2[EE/2];
        #pragma unroll
        for (int e = 0; e < EE/2; ++e) te2[e] = *(const v2f*)(bp + 2*e);
        #pragma unroll
        for (int o = 0; o < OO; ++o) {
            float ov = to2[o>>1][o&1];
            v2f hd; hd[0] = ov; hd[1] = ov;
            const v2f* wr = (const v2f*)(Wp + o*EE);
            #pragma unroll
            for (int e = 0; e < EE/2; ++e)
                te2[e] = pkfma(hd, wr[e], te2[e]);
        }

        // write tok row r = l*16 + w; chunk cc placed at slot (cc ^ (l&3)) to break
        // the all-lanes-same-slot write conflict (reader un-swizzles with (r>>4)&3 == l&3).
        const int r  = l*16 + w;
        float* row   = lds + r*TOKS;
        const int xs = l & 3;
        #pragma unroll
        for (int cc = 0; cc < 4; ++cc) {
            float4 v;
            v.x = te2[2*cc][0];   v.y = te2[2*cc][1];
            v.z = te2[2*cc+1][0]; v.w = te2[2*cc+1][1];
            *(float4*)(row + ((cc ^ xs) * 4)) = v;
        }
    }
    __syncthreads();   // tok complete

    // ================= Phase 2: attention =================
    const int f  = t & 15;     // token
    const int bl = t >> 4;     // local batch 0..63 (16-lane group = one batch)
    const int gb = blockIdx.x * NB + bl;   // global batch

    // read own tok row (row index == t), un-swizzle chunks
    v2f tk[8];
    {
        const float* row = lds + t*TOKS;
        const int xs = (t >> 4) & 3;
        #pragma unroll
        for (int cc = 0; cc < 4; ++cc) {
            float4 v = *(const float4*)(row + ((cc ^ xs) * 4));
            tk[2*cc][0]   = v.x; tk[2*cc][1]   = v.y;
            tk[2*cc+1][0] = v.z; tk[2*cc+1][1] = v.w;
        }
    }
    __syncthreads();   // all tok reads done; kv may overwrite the buffer

    // qkv = tok @ Wqkv + bqkv   (acc2[0:8]=q, [8:16]=k, [16:24]=v; weights uniform -> s_load)
    v2f acc2[24];
    #pragma unroll
    for (int i = 0; i < 24; ++i) acc2[i] = *(const v2f*)(bqkv + 2*i);
    #pragma unroll
    for (int e = 0; e < EE; ++e) {
        float tv = tk[e>>1][e&1];
        v2f hd; hd[0] = tv; hd[1] = tv;
        const v2f* wr = (const v2f*)(Wqkv + e*48);
        #pragma unroll
        for (int i = 0; i < 24; ++i)
            acc2[i] = pkfma(hd, wr[i], acc2[i]);
    }

    // park k,v rows (producer/consumer are the same wave: HW lgkmcnt ordering, no barrier)
    {
        float* kr = lds + bl*KVS + f*16;
        float* vr = kr + 256;
        #pragma unroll
        for (int cc = 0; cc < 4; ++cc) {
            float4 v;
            v.x = acc2[8+2*cc][0]; v.y = acc2[8+2*cc][1];
            v.z = acc2[9+2*cc][0]; v.w = acc2[9+2*cc][1];
            *(float4*)(kr + cc*4) = v;
        }
        #pragma unroll
        for (int cc = 0; cc < 4; ++cc) {
            float4 v;
            v.x = acc2[16+2*cc][0]; v.y = acc2[16+2*cc][1];
            v.z = acc2[17+2*cc][0]; v.w = acc2[17+2*cc][1];
            *(float4*)(vr + cc*4) = v;
        }
    }

    // scores: own q row vs all 16 k rows (broadcast LDS reads), scale 1/sqrt(16)
    float s[16];
    #pragma unroll
    for (int kk = 0; kk < 16; ++kk) {
        const float4* kr4 = (const float4*)(lds + bl*KVS + kk*16);
        float4 k0 = kr4[0], k1 = kr4[1], k2 = kr4[2], k3 = kr4[3];
        v2f d = {0.f, 0.f};
        v2f kp;
        kp[0]=k0.x; kp[1]=k0.y; d = pkfma(acc2[0], kp, d);
        kp[0]=k0.z; kp[1]=k0.w; d = pkfma(acc2[1], kp, d);
        kp[0]=k1.x; kp[1]=k1.y; d = pkfma(acc2[2], kp, d);
        kp[0]=k1.z; kp[1]=k1.w; d = pkfma(acc2[3], kp, d);
        kp[0]=k2.x; kp[1]=k2.y; d = pkfma(acc2[4], kp, d);
        kp[0]=k2.z; kp[1]=k2.w; d = pkfma(acc2[5], kp, d);
        kp[0]=k3.x; kp[1]=k3.y; d = pkfma(acc2[6], kp, d);
        kp[0]=k3.z; kp[1]=k3.w; d = pkfma(acc2[7], kp, d);
        s[kk] = (d[0] + d[1]) * 0.25f;
    }

    // stable softmax over own row
    float m = s[0];
    #pragma unroll
    for (int kk = 1; kk < 16; ++kk) m = fmaxf(m, s[kk]);
    float sum = 0.f;
    #pragma unroll
    for (int kk = 0; kk < 16; ++kk) { s[kk] = __expf(s[kk] - m); sum += s[kk]; }
    const float inv = 1.0f / sum;
    #pragma unroll
    for (int kk = 0; kk < 16; ++kk) s[kk] *= inv;

    // column sums across the 16 token-lanes -> 16*abar (replicated)
    #pragma unroll
    for (int kk = 0; kk < 16; ++kk) s[kk] = sum16(s[kk]);

    // pooled_v[f] = (1/16) * sum_kk (16*abar[kk]/16) * v[kk][f]
    float pvf = 0.f;
    #pragma unroll
    for (int kk = 0; kk < 16; ++kk)
        pvf = fmaf(s[kk], lds[bl*KVS + 256 + kk*16 + f], pvf);
    pvf *= 0.0625f;

    // wof[f] = Wo[f][:] . Wf
    float wof;
    {
        const float4* wr = (const float4*)(Wo + f*EE);
        float4 w0 = wr[0], w1 = wr[1], w2 = wr[2], w3 = wr[3];
        wof = w0.x*Wf[0]  + w0.y*Wf[1]  + w0.z*Wf[2]  + w0.w*Wf[3]
            + w1.x*Wf[4]  + w1.y*Wf[5]  + w1.z*Wf[6]  + w1.w*Wf[7]
            + w2.x*Wf[8]  + w2.y*Wf[9]  + w2.z*Wf[10] + w2.w*Wf[11]
            + w3.x*Wf[12] + w3.y*Wf[13] + w3.z*Wf[14] + w3.w*Wf[15];
    }

    float c = fmaf(pvf, wof, bo[f]*Wf[f]);
    c = sum16(c);

    if (f == 0) {
        float r = c + bf[0];
        out[gb] = (r >= 0.f) ? r : 0.01f*r;
    }
}

extern "C" void kernel_launch(void* const* d_in, const int* in_sizes, int n_in,
                              void* d_out, int out_size, void* d_ws, size_t ws_size,
                              hipStream_t stream)
{
    const float* x    = (const float*)d_in[0];
    const float* W1   = (const float*)d_in[1];
    const float* b1   = (const float*)d_in[2];
    const float* W2   = (const float*)d_in[3];
    const float* b2   = (const float*)d_in[4];
    const float* W3   = (const float*)d_in[5];
    const float* b3   = (const float*)d_in[6];
    const float* Wp   = (const float*)d_in[7];
    const float* bp   = (const float*)d_in[8];
    const float* Wqkv = (const float*)d_in[9];
    const float* bqkv = (const float*)d_in[10];
    const float* Wo   = (const float*)d_in[11];
    const float* bo   = (const float*)d_in[12];
    const float* Wf   = (const float*)d_in[13];
    const float* bf   = (const float*)d_in[14];
    float* out = (float*)d_out;

    spinn_fused_kernel<<<dim3(BB/NB), dim3(1024), 0, stream>>>(
        x, W1, b1, W2, b2, W3, b3, Wp, bp, Wqkv, bqkv, Wo, bo, Wf, bf, out);
}

// Round 7
// 212.323 us; speedup vs baseline: 6.6828x; 6.6828x over previous
//
#include <hip/hip_runtime.h>

#define BB 32768
#define FF 16
#define HH 64
#define OO 32
#define EE 16

// ---------------- Phase 1: per-feature subnets -> tok [F][B][E] ----------------
// PROVEN SHAPE (round 2: 116us, 52 VGPR, zero scratch) — do not perturb.
// f = blockIdx.y (truly uniform -> weights via s_load into SGPRs).
__global__ __launch_bounds__(256, 4) void spinn_subnet_kernel(
    const float* __restrict__ x,
    const float* __restrict__ W1, const float* __restrict__ b1,
    const float* __restrict__ W2, const float* __restrict__ b2,
    const float* __restrict__ W3, const float* __restrict__ b3,
    const float* __restrict__ Wp, const float* __restrict__ bp,
    float* __restrict__ tok)
{
    const int f = blockIdx.y;
    const int t = threadIdx.x;
    const int b = blockIdx.x * 256 + t;

    const float* __restrict__ w1  = W1 + f*HH;      // [64]   (W1[f,0,:])
    const float* __restrict__ bb1 = b1 + f*HH;
    const float* __restrict__ w2  = W2 + f*HH*HH;   // [64][64]
    const float* __restrict__ bb2 = b2 + f*HH;
    const float* __restrict__ w3  = W3 + f*HH*OO;   // [64][32]
    const float* __restrict__ bb3 = b3 + f*OO;

    const float xv = x[(size_t)b*FF + f];

    // ---- layer 1+2: h2 = b2 + sum_j leaky(x*w1[j]+b1[j]) * w2[j][:] ----
    float h2[HH];
    #pragma unroll
    for (int k = 0; k < HH; ++k) h2[k] = bb2[k];

    #pragma unroll 2
    for (int j = 0; j < HH; ++j) {       // rolled: hot loop stays in icache
        float h1 = fmaf(xv, w1[j], bb1[j]);
        h1 = (h1 >= 0.f) ? h1 : 0.01f*h1;
        #pragma unroll
        for (int k = 0; k < HH; ++k)
            h2[k] = fmaf(h1, w2[j*HH + k], h2[k]);   // SGPR weight operand
    }
    #pragma unroll
    for (int k = 0; k < HH; ++k) { float v = h2[k]; h2[k] = (v >= 0.f) ? v : 0.01f*v; }

    // ---- layer 3 (j fully unrolled: h2[j] must be statically indexed) ----
    float to_[OO];
    #pragma unroll
    for (int o = 0; o < OO; ++o) to_[o] = bb3[o];
    #pragma unroll
    for (int j = 0; j < HH; ++j) {
        const float hv = h2[j];
        #pragma unroll
        for (int o = 0; o < OO; ++o)
            to_[o] = fmaf(hv, w3[j*OO + o], to_[o]);
    }

    // ---- proj O->E (o fully unrolled: to_[o] statically indexed) ----
    float te[EE];
    #pragma unroll
    for (int e = 0; e < EE; ++e) te[e] = bp[e];
    #pragma unroll
    for (int o = 0; o < OO; ++o) {
        const float ov = to_[o];
        #pragma unroll
        for (int e = 0; e < EE; ++e)
            te[e] = fmaf(ov, Wp[o*EE + e], te[e]);
    }

    float4* dst = (float4*)(tok + ((size_t)f*BB + (size_t)b)*EE);
    dst[0] = make_float4(te[0],  te[1],  te[2],  te[3]);
    dst[1] = make_float4(te[4],  te[5],  te[6],  te[7]);
    dst[2] = make_float4(te[8],  te[9],  te[10], te[11]);
    dst[3] = make_float4(te[12], te[13], te[14], te[15]);
}

// ---------------- Phase 2: qkv + attention + pool + final FC ----------------
// Restructured for the empirical 64-VGPR budget: q/k pass (peak 48 floats),
// then v pass (peak 48). k,v parked in LDS; each batch's 16 tokens live in
// one 16-lane group of one wave -> intra-wave ds_write/ds_read ordering, no
// __syncthreads needed.
#define KVPAD 260   // floats per batch row: 256 + 4 pad

// Full-rate DPP butterfly sum over each aligned 16-lane group (replicated).
__device__ __forceinline__ float sum16(float v) {
    int i;
    i = __builtin_amdgcn_update_dpp(0, __float_as_int(v), 0xB1,  0xF, 0xF, true); v += __int_as_float(i); // xor 1
    i = __builtin_amdgcn_update_dpp(0, __float_as_int(v), 0x4E,  0xF, 0xF, true); v += __int_as_float(i); // xor 2
    i = __builtin_amdgcn_update_dpp(0, __float_as_int(v), 0x141, 0xF, 0xF, true); v += __int_as_float(i); // half-mirror
    i = __builtin_amdgcn_update_dpp(0, __float_as_int(v), 0x140, 0xF, 0xF, true); v += __int_as_float(i); // row mirror
    return v;
}

__global__ __launch_bounds__(256, 4) void spinn_attn_kernel(
    const float* __restrict__ tok,
    const float* __restrict__ Wqkv, const float* __restrict__ bqkv,
    const float* __restrict__ Wo,   const float* __restrict__ bo,
    const float* __restrict__ Wf,   const float* __restrict__ bf,
    float* __restrict__ out)
{
    __shared__ __align__(16) float kb[16*KVPAD];
    __shared__ __align__(16) float vb[16*KVPAD];

    const int t  = threadIdx.x;
    const int f  = t & 15;        // token index (16-lane group)
    const int bl = t >> 4;        // local batch 0..15
    const int gb = blockIdx.x * 16 + bl;

    float tokv[EE];
    {
        const float4* tp = (const float4*)(tok + ((size_t)f*BB + (size_t)gb)*EE);
        float4 v0 = tp[0], v1 = tp[1], v2 = tp[2], v3 = tp[3];
        tokv[0]=v0.x; tokv[1]=v0.y; tokv[2]=v0.z; tokv[3]=v0.w;
        tokv[4]=v1.x; tokv[5]=v1.y; tokv[6]=v1.z; tokv[7]=v1.w;
        tokv[8]=v2.x; tokv[9]=v2.y; tokv[10]=v2.z; tokv[11]=v2.w;
        tokv[12]=v3.x; tokv[13]=v3.y; tokv[14]=v3.z; tokv[15]=v3.w;
    }

    // ---- pass A: q (kept in regs) + k (-> LDS). Peak live: tokv16+q16+kx16=48
    float q[EE], kx[EE];
    #pragma unroll
    for (int i = 0; i < EE; ++i) { q[i] = bqkv[i]; kx[i] = bqkv[EE + i]; }
    #pragma unroll
    for (int e = 0; e < EE; ++e) {
        const float tv = tokv[e];
        #pragma unroll
        for (int i = 0; i < EE; ++i) {
            q[i]  = fmaf(tv, Wqkv[e*48 + i],      q[i]);
            kx[i] = fmaf(tv, Wqkv[e*48 + EE + i], kx[i]);
        }
    }
    {
        float4* kr = (float4*)(kb + bl*KVPAD + f*16);
        kr[0] = make_float4(kx[0],  kx[1],  kx[2],  kx[3]);
        kr[1] = make_float4(kx[4],  kx[5],  kx[6],  kx[7]);
        kr[2] = make_float4(kx[8],  kx[9],  kx[10], kx[11]);
        kr[3] = make_float4(kx[12], kx[13], kx[14], kx[15]);
    }

    // ---- pass B: v (-> LDS). kx registers recycle into vx.
    {
        float vx[EE];
        #pragma unroll
        for (int i = 0; i < EE; ++i) vx[i] = bqkv[2*EE + i];
        #pragma unroll
        for (int e = 0; e < EE; ++e) {
            const float tv = tokv[e];
            #pragma unroll
            for (int i = 0; i < EE; ++i)
                vx[i] = fmaf(tv, Wqkv[e*48 + 2*EE + i], vx[i]);
        }
        float4* vr = (float4*)(vb + bl*KVPAD + f*16);
        vr[0] = make_float4(vx[0],  vx[1],  vx[2],  vx[3]);
        vr[1] = make_float4(vx[4],  vx[5],  vx[6],  vx[7]);
        vr[2] = make_float4(vx[8],  vx[9],  vx[10], vx[11]);
        vr[3] = make_float4(vx[12], vx[13], vx[14], vx[15]);
    }

    // ---- scores: own q row vs all 16 k rows (LDS broadcast reads), scale 0.25
    float s[16];
    #pragma unroll
    for (int kk = 0; kk < 16; ++kk) {
        const float4* krow = (const float4*)(kb + bl*KVPAD + kk*16);
        float4 k0 = krow[0], k1 = krow[1], k2 = krow[2], k3 = krow[3];
        float d = q[0]*k0.x  + q[1]*k0.y  + q[2]*k0.z  + q[3]*k0.w
                + q[4]*k1.x  + q[5]*k1.y  + q[6]*k1.z  + q[7]*k1.w
                + q[8]*k2.x  + q[9]*k2.y  + q[10]*k2.z + q[11]*k2.w
                + q[12]*k3.x + q[13]*k3.y + q[14]*k3.z + q[15]*k3.w;
        s[kk] = d * 0.25f;
    }

    // ---- stable softmax over own row
    float m = s[0];
    #pragma unroll
    for (int kk = 1; kk < 16; ++kk) m = fmaxf(m, s[kk]);
    float sum = 0.f;
    #pragma unroll
    for (int kk = 0; kk < 16; ++kk) { s[kk] = __expf(s[kk] - m); sum += s[kk]; }
    const float inv = 1.0f / sum;
    #pragma unroll
    for (int kk = 0; kk < 16; ++kk) s[kk] *= inv;

    // ---- column sums across the 16 token-lanes -> 16*abar (replicated)
    #pragma unroll
    for (int kk = 0; kk < 16; ++kk) s[kk] = sum16(s[kk]);

    // ---- pooled_v[f] = (1/16) * sum_kk abar[kk] * v[kk][f]
    float pvf = 0.f;
    #pragma unroll
    for (int kk = 0; kk < 16; ++kk)
        pvf = fmaf(s[kk], vb[bl*KVPAD + kk*16 + f], pvf);
    pvf *= 0.0625f;

    // ---- wof[f] = Wo[f][:] . Wf ; out = leaky(sum_f pv[f]*wof[f] + bo.Wf + bf)
    float wof;
    {
        const float4* wr = (const float4*)(Wo + f*EE);
        float4 w0 = wr[0], w1 = wr[1], w2 = wr[2], w3 = wr[3];
        wof = w0.x*Wf[0]  + w0.y*Wf[1]  + w0.z*Wf[2]  + w0.w*Wf[3]
            + w1.x*Wf[4]  + w1.y*Wf[5]  + w1.z*Wf[6]  + w1.w*Wf[7]
            + w2.x*Wf[8]  + w2.y*Wf[9]  + w2.z*Wf[10] + w2.w*Wf[11]
            + w3.x*Wf[12] + w3.y*Wf[13] + w3.z*Wf[14] + w3.w*Wf[15];
    }

    float c = fmaf(pvf, wof, bo[f]*Wf[f]);
    c = sum16(c);

    if (f == 0) {
        float r = c + bf[0];
        out[gb] = (r >= 0.f) ? r : 0.01f*r;
    }
}

extern "C" void kernel_launch(void* const* d_in, const int* in_sizes, int n_in,
                              void* d_out, int out_size, void* d_ws, size_t ws_size,
                              hipStream_t stream)
{
    const float* x    = (const float*)d_in[0];
    const float* W1   = (const float*)d_in[1];
    const float* b1   = (const float*)d_in[2];
    const float* W2   = (const float*)d_in[3];
    const float* b2   = (const float*)d_in[4];
    const float* W3   = (const float*)d_in[5];
    const float* b3   = (const float*)d_in[6];
    const float* Wp   = (const float*)d_in[7];
    const float* bp   = (const float*)d_in[8];
    const float* Wqkv = (const float*)d_in[9];
    const float* bqkv = (const float*)d_in[10];
    const float* Wo   = (const float*)d_in[11];
    const float* bo   = (const float*)d_in[12];
    const float* Wf   = (const float*)d_in[13];
    const float* bf   = (const float*)d_in[14];
    float* out = (float*)d_out;
    float* tok = (float*)d_ws;   // [F][B][E] fp32 = 32 MB scratch

    dim3 g1(BB/256, FF);
    spinn_subnet_kernel<<<g1, 256, 0, stream>>>(x, W1, b1, W2, b2, W3, b3, Wp, bp, tok);
    spinn_attn_kernel<<<BB/16, 256, 0, stream>>>(tok, Wqkv, bqkv, Wo, bo, Wf, bf, out);
}

// Round 9
// 196.938 us; speedup vs baseline: 7.2048x; 1.0781x over previous
//
#include <hip/hip_runtime.h>

#define BB 32768
#define FF 16
#define HH 64
#define OO 32
#define EE 16

typedef float v2f __attribute__((ext_vector_type(2)));

__device__ __forceinline__ v2f pkfma(v2f a, v2f b, v2f c) {
    return __builtin_elementwise_fma(a, b, c);   // -> v_pk_fma_f32 (fp32 peak = packed rate)
}

// ---------------- Phase 1: per-feature subnets -> tok [B][F][E] ----------------
// Round-7 proven structure (f = blockIdx.y -> truly uniform weights via s_load).
// Round-8 change: packed-pair FMAs (v_pk_fma_f32) to halve VALU instruction count.
__global__ __launch_bounds__(256, 4) void spinn_subnet_kernel(
    const float* __restrict__ x,
    const float* __restrict__ W1, const float* __restrict__ b1,
    const float* __restrict__ W2, const float* __restrict__ b2,
    const float* __restrict__ W3, const float* __restrict__ b3,
    const float* __restrict__ Wp, const float* __restrict__ bp,
    float* __restrict__ tok)
{
    const int f = blockIdx.y;
    const int t = threadIdx.x;
    const int b = blockIdx.x * 256 + t;

    const float* __restrict__ w1  = W1 + f*HH;      // [64]   (W1[f,0,:])
    const float* __restrict__ bb1 = b1 + f*HH;
    const float* __restrict__ w2  = W2 + f*HH*HH;   // [64][64]
    const float* __restrict__ bb2 = b2 + f*HH;
    const float* __restrict__ w3  = W3 + f*HH*OO;   // [64][32]
    const float* __restrict__ bb3 = b3 + f*OO;

    const float xv = x[(size_t)b*FF + f];

    // ---- layer 1+2: h2 = b2 + sum_j leaky(x*w1[j]+b1[j]) * w2[j][:] ----
    v2f h2[HH/2];
    #pragma unroll
    for (int k = 0; k < HH/2; ++k) h2[k] = *(const v2f*)(bb2 + 2*k);

    #pragma unroll 2
    for (int j = 0; j < HH; ++j) {       // rolled: hot loop stays in icache
        float h1 = fmaf(xv, w1[j], bb1[j]);
        h1 = (h1 >= 0.f) ? h1 : 0.01f*h1;
        v2f hd; hd[0] = h1; hd[1] = h1;
        const v2f* wr = (const v2f*)(w2 + j*HH);   // uniform -> s_load pairs
        #pragma unroll
        for (int k = 0; k < HH/2; ++k)
            h2[k] = pkfma(hd, wr[k], h2[k]);
    }
    #pragma unroll
    for (int k = 0; k < HH/2; ++k) {
        float a0 = h2[k][0], a1 = h2[k][1];
        h2[k][0] = (a0 >= 0.f) ? a0 : 0.01f*a0;
        h2[k][1] = (a1 >= 0.f) ? a1 : 0.01f*a1;
    }

    // ---- layer 3 (j fully unrolled: h2 statically indexed) ----
    v2f to2[OO/2];
    #pragma unroll
    for (int o = 0; o < OO/2; ++o) to2[o] = *(const v2f*)(bb3 + 2*o);
    #pragma unroll
    for (int j = 0; j < HH; ++j) {
        const float hv = h2[j>>1][j&1];
        v2f hd; hd[0] = hv; hd[1] = hv;
        const v2f* wr = (const v2f*)(w3 + j*OO);
        #pragma unroll
        for (int o = 0; o < OO/2; ++o)
            to2[o] = pkfma(hd, wr[o], to2[o]);
    }

    // ---- proj O->E (o fully unrolled: to2 statically indexed) ----
    v2f te2[EE/2];
    #pragma unroll
    for (int e = 0; e < EE/2; ++e) te2[e] = *(const v2f*)(bp + 2*e);
    #pragma unroll
    for (int o = 0; o < OO; ++o) {
        const float ov = to2[o>>1][o&1];
        v2f hd; hd[0] = ov; hd[1] = ov;
        const v2f* wr = (const v2f*)(Wp + o*EE);
        #pragma unroll
        for (int e = 0; e < EE/2; ++e)
            te2[e] = pkfma(hd, wr[e], te2[e]);
    }

    // tok layout [B][F][E]: attn wave reads become fully contiguous (4 KB/wave).
    // This write is 1KB-strided per lane -- non-critical (hidden behind compute).
    float4* dst = (float4*)(tok + ((size_t)b*FF + (size_t)f)*EE);
    dst[0] = make_float4(te2[0][0], te2[0][1], te2[1][0], te2[1][1]);
    dst[1] = make_float4(te2[2][0], te2[2][1], te2[3][0], te2[3][1]);
    dst[2] = make_float4(te2[4][0], te2[4][1], te2[5][0], te2[5][1]);
    dst[3] = make_float4(te2[6][0], te2[6][1], te2[7][0], te2[7][1]);
}

// ---------------- Phase 2: qkv + attention + pool + final FC ----------------
// Round-7 structure (q/k pass then v pass, k/v in LDS, intra-wave ordering, no
// barriers). Round-8 change: tok reads are now contiguous ([B][F][E] layout).
#define KVPAD 260   // floats per batch row: 256 + 4 pad

// Full-rate DPP butterfly sum over each aligned 16-lane group (replicated).
__device__ __forceinline__ float sum16(float v) {
    int i;
    i = __builtin_amdgcn_update_dpp(0, __float_as_int(v), 0xB1,  0xF, 0xF, true); v += __int_as_float(i); // xor 1
    i = __builtin_amdgcn_update_dpp(0, __float_as_int(v), 0x4E,  0xF, 0xF, true); v += __int_as_float(i); // xor 2
    i = __builtin_amdgcn_update_dpp(0, __float_as_int(v), 0x141, 0xF, 0xF, true); v += __int_as_float(i); // half-mirror
    i = __builtin_amdgcn_update_dpp(0, __float_as_int(v), 0x140, 0xF, 0xF, true); v += __int_as_float(i); // row mirror
    return v;
}

__global__ __launch_bounds__(256, 4) void spinn_attn_kernel(
    const float* __restrict__ tok,
    const float* __restrict__ Wqkv, const float* __restrict__ bqkv,
    const float* __restrict__ Wo,   const float* __restrict__ bo,
    const float* __restrict__ Wf,   const float* __restrict__ bf,
    float* __restrict__ out)
{
    __shared__ __align__(16) float kb[16*KVPAD];
    __shared__ __align__(16) float vb[16*KVPAD];

    const int t  = threadIdx.x;
    const int f  = t & 15;        // token index (16-lane group)
    const int bl = t >> 4;        // local batch 0..15
    const int gb = blockIdx.x * 16 + bl;

    float tokv[EE];
    {
        // [B][F][E]: block reads 16 KB contiguous; wave reads 4 KB contiguous.
        const float4* tp = (const float4*)(tok + ((size_t)gb*FF + (size_t)f)*EE);
        float4 v0 = tp[0], v1 = tp[1], v2 = tp[2], v3 = tp[3];
        tokv[0]=v0.x; tokv[1]=v0.y; tokv[2]=v0.z; tokv[3]=v0.w;
        tokv[4]=v1.x; tokv[5]=v1.y; tokv[6]=v1.z; tokv[7]=v1.w;
        tokv[8]=v2.x; tokv[9]=v2.y; tokv[10]=v2.z; tokv[11]=v2.w;
        tokv[12]=v3.x; tokv[13]=v3.y; tokv[14]=v3.z; tokv[15]=v3.w;
    }

    // ---- pass A: q (kept in regs) + k (-> LDS). Peak live: tokv16+q16+kx16=48
    float q[EE], kx[EE];
    #pragma unroll
    for (int i = 0; i < EE; ++i) { q[i] = bqkv[i]; kx[i] = bqkv[EE + i]; }
    #pragma unroll
    for (int e = 0; e < EE; ++e) {
        const float tv = tokv[e];
        #pragma unroll
        for (int i = 0; i < EE; ++i) {
            q[i]  = fmaf(tv, Wqkv[e*48 + i],      q[i]);
            kx[i] = fmaf(tv, Wqkv[e*48 + EE + i], kx[i]);
        }
    }
    {
        float4* kr = (float4*)(kb + bl*KVPAD + f*16);
        kr[0] = make_float4(kx[0],  kx[1],  kx[2],  kx[3]);
        kr[1] = make_float4(kx[4],  kx[5],  kx[6],  kx[7]);
        kr[2] = make_float4(kx[8],  kx[9],  kx[10], kx[11]);
        kr[3] = make_float4(kx[12], kx[13], kx[14], kx[15]);
    }

    // ---- pass B: v (-> LDS). kx registers recycle into vx.
    {
        float vx[EE];
        #pragma unroll
        for (int i = 0; i < EE; ++i) vx[i] = bqkv[2*EE + i];
        #pragma unroll
        for (int e = 0; e < EE; ++e) {
            const float tv = tokv[e];
            #pragma unroll
            for (int i = 0; i < EE; ++i)
                vx[i] = fmaf(tv, Wqkv[e*48 + 2*EE + i], vx[i]);
        }
        float4* vr = (float4*)(vb + bl*KVPAD + f*16);
        vr[0] = make_float4(vx[0],  vx[1],  vx[2],  vx[3]);
        vr[1] = make_float4(vx[4],  vx[5],  vx[6],  vx[7]);
        vr[2] = make_float4(vx[8],  vx[9],  vx[10], vx[11]);
        vr[3] = make_float4(vx[12], vx[13], vx[14], vx[15]);
    }

    // ---- scores: own q row vs all 16 k rows (LDS broadcast reads), scale 0.25
    float s[16];
    #pragma unroll
    for (int kk = 0; kk < 16; ++kk) {
        const float4* krow = (const float4*)(kb + bl*KVPAD + kk*16);
        float4 k0 = krow[0], k1 = krow[1], k2 = krow[2], k3 = krow[3];
        float d = q[0]*k0.x  + q[1]*k0.y  + q[2]*k0.z  + q[3]*k0.w
                + q[4]*k1.x  + q[5]*k1.y  + q[6]*k1.z  + q[7]*k1.w
                + q[8]*k2.x  + q[9]*k2.y  + q[10]*k2.z + q[11]*k2.w
                + q[12]*k3.x + q[13]*k3.y + q[14]*k3.z + q[15]*k3.w;
        s[kk] = d * 0.25f;
    }

    // ---- stable softmax over own row
    float m = s[0];
    #pragma unroll
    for (int kk = 1; kk < 16; ++kk) m = fmaxf(m, s[kk]);
    float sum = 0.f;
    #pragma unroll
    for (int kk = 0; kk < 16; ++kk) { s[kk] = __expf(s[kk] - m); sum += s[kk]; }
    const float inv = 1.0f / sum;
    #pragma unroll
    for (int kk = 0; kk < 16; ++kk) s[kk] *= inv;

    // ---- column sums across the 16 token-lanes -> 16*abar (replicated)
    #pragma unroll
    for (int kk = 0; kk < 16; ++kk) s[kk] = sum16(s[kk]);

    // ---- pooled_v[f] = (1/16) * sum_kk abar[kk] * v[kk][f]
    float pvf = 0.f;
    #pragma unroll
    for (int kk = 0; kk < 16; ++kk)
        pvf = fmaf(s[kk], vb[bl*KVPAD + kk*16 + f], pvf);
    pvf *= 0.0625f;

    // ---- wof[f] = Wo[f][:] . Wf ; out = leaky(sum_f pv[f]*wof[f] + bo.Wf + bf)
    float wof;
    {
        const float4* wr = (const float4*)(Wo + f*EE);
        float4 w0 = wr[0], w1 = wr[1], w2 = wr[2], w3 = wr[3];
        wof = w0.x*Wf[0]  + w0.y*Wf[1]  + w0.z*Wf[2]  + w0.w*Wf[3]
            + w1.x*Wf[4]  + w1.y*Wf[5]  + w1.z*Wf[6]  + w1.w*Wf[7]
            + w2.x*Wf[8]  + w2.y*Wf[9]  + w2.z*Wf[10] + w2.w*Wf[11]
            + w3.x*Wf[12] + w3.y*Wf[13] + w3.z*Wf[14] + w3.w*Wf[15];
    }

    float c = fmaf(pvf, wof, bo[f]*Wf[f]);
    c = sum16(c);

    if (f == 0) {
        float r = c + bf[0];
        out[gb] = (r >= 0.f) ? r : 0.01f*r;
    }
}

extern "C" void kernel_launch(void* const* d_in, const int* in_sizes, int n_in,
                              void* d_out, int out_size, void* d_ws, size_t ws_size,
                              hipStream_t stream)
{
    const float* x    = (const float*)d_in[0];
    const float* W1   = (const float*)d_in[1];
    const float* b1   = (const float*)d_in[2];
    const float* W2   = (const float*)d_in[3];
    const float* b2   = (const float*)d_in[4];
    const float* W3   = (const float*)d_in[5];
    const float* b3   = (const float*)d_in[6];
    const float* Wp   = (const float*)d_in[7];
    const float* bp   = (const float*)d_in[8];
    const float* Wqkv = (const float*)d_in[9];
    const float* bqkv = (const float*)d_in[10];
    const float* Wo   = (const float*)d_in[11];
    const float* bo   = (const float*)d_in[12];
    const float* Wf   = (const float*)d_in[13];
    const float* bf   = (const float*)d_in[14];
    float* out = (float*)d_out;
    float* tok = (float*)d_ws;   // [B][F][E] fp32 = 32 MB scratch

    dim3 g1(BB/256, FF);
    spinn_subnet_kernel<<<g1, 256, 0, stream>>>(x, W1, b1, W2, b2, W3, b3, Wp, bp, tok);
    spinn_attn_kernel<<<BB/16, 256, 0, stream>>>(tok, Wqkv, bqkv, Wo, bo, Wf, bf, out);
}